// Round 10
// baseline (73.800 us; speedup 1.0000x reference)
//
#include <hip/hip_runtime.h>
#include <hip/hip_bf16.h>
#include <math.h>

#define BATCH 256
#define SEQL  4096
#define DIMC  256
#define NPAT  160
#define CNT   (BATCH * SEQL)     // per-stream element count (over B,L)
#define EPS   1e-3f

typedef unsigned int uint;
typedef unsigned short ushort_t;

// ---------------- shared helpers ----------------------------------------------
__device__ __forceinline__ int pad_mask(int type) {
    return (type == 0) ? 0 : (type == 1) ? 3 : (type == 2) ? 1 : (type == 3) ? 16 : 24;
}

// tap value for extended-pattern q, index k in [0,6): k==5 is the constant 1.
__device__ __forceinline__ float tap6(int q, int k) {
    if (k == 5) return 1.0f;
    const int type = q >> 5, bits = q & 31;
    const int pm = pad_mask(type);
    if ((pm >> k) & 1) return 0.0f;
    return ((bits >> k) & 1) ? 1.0f : -1.0f;
}

__device__ __forceinline__ float fast_elu(float x) {
    return x > 0.0f ? x : (__expf(x) - 1.0f);
}

__device__ __forceinline__ int pat_type(int t) {
    if (t >= 2 && t < SEQL - 2) return 0;
    if (t == 0) return 1;
    if (t == 1) return 2;
    if (t == SEQL - 2) return 3;
    return 4;
}

struct PtrPack { const float* p[18]; };  // per stream: Wc, bc, g, be, Wf, bf

// =============================================================================
// k_zero: zero hist[320] + done counter (word 320). 1 block.
// =============================================================================
__global__ __launch_bounds__(512) void k_zero(uint* __restrict__ ws0) {
    if (threadIdx.x < 321) ws0[threadIdx.x] = 0u;
}

// =============================================================================
// k_prep: bit-pack rows (ballot), per-position codes, LDS hist -> global
// atomic hist (1.3 KB total). 256 blocks x 512 threads.  [proven]
// =============================================================================
__global__ __launch_bounds__(512) void k_prep(const float* __restrict__ x,
                                              const int* __restrict__ perms,
                                              uint* __restrict__ hist,
                                              ushort_t* __restrict__ codes) {
    __shared__ uint xw[130];    // bit-packed row, 1-word zero sentinel each end
    __shared__ uint xwI[130];
    __shared__ uint h[2 * NPAT];
    const int b = blockIdx.x, tid = threadIdx.x;
    const int lane = tid & 63;

    for (int i = tid; i < 2 * NPAT; i += 512) h[i] = 0;
    if (tid < 2) { xw[tid * 129] = 0; xwI[tid * 129] = 0; }

    const float* xr = x + (size_t)b * SEQL;
    const int* pr = perms + (size_t)b * SEQL;

#pragma unroll
    for (int it = 0; it < 8; ++it) {
        const int i = it * 512 + tid;
        const unsigned long long m = __ballot(xr[i] > 0.5f);
        if (lane == 0) {
            const int w = 1 + ((it * 512 + (tid & ~63)) >> 5);
            xw[w] = (uint)m;
            xw[w + 1] = (uint)(m >> 32);
        }
    }
    __syncthreads();
#pragma unroll
    for (int it = 0; it < 8; ++it) {
        const int i = it * 512 + tid;
        const int p = pr[i];
        const unsigned long long m = __ballot(((xw[1 + (p >> 5)] >> (p & 31)) & 1u) != 0u);
        if (lane == 0) {
            const int w = 1 + ((it * 512 + (tid & ~63)) >> 5);
            xwI[w] = (uint)m;
            xwI[w + 1] = (uint)(m >> 32);
        }
    }
    __syncthreads();

    const int t0 = tid * 8;
    const int w = (t0 + 30) >> 5;
    const int sh0 = (t0 + 30) & 31;
    const unsigned long long Wd = (unsigned long long)xw[w] | ((unsigned long long)xw[w + 1] << 32);
    const unsigned long long Wi = (unsigned long long)xwI[w] | ((unsigned long long)xwI[w + 1] << 32);
    int c[8];
#pragma unroll
    for (int r = 0; r < 8; ++r) {
        const int t = t0 + r;
        const int type = pat_type(t);
        const int qd = type * 32 + (int)((Wd >> (sh0 + r)) & 31ull);
        const int qp = type * 32 + (int)((Wi >> (sh0 + r)) & 31ull);
        atomicAdd(&h[qd], 1u);
        atomicAdd(&h[NPAT + qp], 1u);
        c[r] = qd | (qp << 8);
    }
    uint4 cv;
    cv.x = (uint)(c[0] | (c[1] << 16));
    cv.y = (uint)(c[2] | (c[3] << 16));
    cv.z = (uint)(c[4] | (c[5] << 16));
    cv.w = (uint)(c[6] | (c[7] << 16));
    *(uint4*)(codes + (size_t)b * SEQL + t0) = cv;
    __syncthreads();

    if (tid < 2 * NPAT) {
        const uint v = h[tid];
        if (v) atomicAdd(&hist[tid], v);
    }
}

// =============================================================================
// k_etab4: 480 blocks x 1024 threads. Each block computes e_tab[bid] (proven
// etab3 math; threads >=256 idle through syncthreads). The LAST block to
// finish (done-counter) runs the proven 1024-thread outtab finish, reading
// e_tab with agent-scope atomic loads (cross-XCD coherence within dispatch).
// =============================================================================
__global__ __launch_bounds__(1024) void k_etab4(PtrPack pk,
                                                const uint* __restrict__ hist,
                                                float* __restrict__ e_tab,
                                                uint* __restrict__ done,
                                                const float* __restrict__ Wm,
                                                const float* __restrict__ gm,
                                                const float* __restrict__ bem,
                                                const float* __restrict__ Wo,
                                                const float* __restrict__ bo,
                                                const float* __restrict__ go,
                                                const float* __restrict__ beo,
                                                float* __restrict__ out_tab) {
    const int bid = blockIdx.x;           // 0..479
    const int j = bid / NPAT, q = bid % NPAT;
    const int tid = threadIdx.x;
    const int lane = tid & 63, w = tid >> 6;

    __shared__ float sh[NPAT];
    __shared__ float m6p[21][8];
    __shared__ float sM6[21];
    __shared__ float red[4];
    __shared__ int sflag;
    // outtab-phase shared
    __shared__ float se[480], snn[480], spre0[480], spre1[480];
    __shared__ float sA[DIMC], sB[DIMC], sWo0[DIMC], sWo1[DIMC];
    __shared__ double wpart[16][4];
    __shared__ double dstat[6];

    // ---- e-table phase (proven etab3 math) ----------------------------------
    if (tid < NPAT) sh[tid] = (float)hist[(j == 2 ? NPAT : 0) + tid];
    __syncthreads();

    if (tid < 168) {
        const int e = tid >> 3, prt = tid & 7;
        int k = 0, rem = e;
        while (rem > 5 - k) { rem -= 6 - k; ++k; }
        const int l = k + rem;
        float S = 0.0f;
        for (int qq = prt * 20; qq < prt * 20 + 20; ++qq)
            S += sh[qq] * tap6(qq, k) * tap6(qq, l);
        m6p[e][prt] = S;
    }
    __syncthreads();
    if (tid < 21) {
        float S = 0.0f;
#pragma unroll
        for (int p = 0; p < 8; ++p) S += m6p[tid][p];
        sM6[tid] = S;
    }
    __syncthreads();

    if (tid < 256) {
        const int c = tid;
        const float* Wc = pk.p[6 * j + 0];
        const float* bc = pk.p[6 * j + 1];
        const float* g  = pk.p[6 * j + 2];
        const float* be = pk.p[6 * j + 3];
        const float* Wf = pk.p[6 * j + 4];

        float w6[6];
#pragma unroll
        for (int k = 0; k < 5; ++k) w6[k] = Wc[k * DIMC + c];
        w6[5] = bc[c];

        double Ey = 0.0, Ey2 = 0.0;
        {
            int e = 0;
#pragma unroll
            for (int k = 0; k < 6; ++k) {
#pragma unroll
                for (int l = k; l < 6; ++l, ++e) {
                    const double p = (double)w6[k] * (double)w6[l] * (double)sM6[e];
                    Ey2 += (l == k) ? p : 2.0 * p;
                    if (l == 5) Ey += (double)w6[k] * (double)sM6[e];
                }
            }
        }
        const double mean = Ey / (double)CNT;
        const double var = Ey2 / (double)CNT - mean * mean;
        const float scale = g[c] * rsqrtf((float)var + EPS);

        float tk[5];
#pragma unroll
        for (int k = 0; k < 5; ++k) tk[k] = tap6(q, k);

        float bn = scale * (w6[5] - (float)mean) + be[c];
#pragma unroll
        for (int k = 0; k < 5; ++k) bn += tk[k] * (scale * w6[k]);
        float v = fast_elu(bn) * Wf[c];

#pragma unroll
        for (int off = 32; off; off >>= 1) v += __shfl_xor(v, off);
        if (lane == 0) red[w] = v;
    }
    __syncthreads();

    if (tid == 0) {
        const float bf = pk.p[6 * j + 5][0];
        const float ev = red[0] + red[1] + red[2] + red[3] + bf;
        __hip_atomic_store(&e_tab[bid], ev, __ATOMIC_RELEASE,
                           __HIP_MEMORY_SCOPE_AGENT);
        const uint old = __hip_atomic_fetch_add(done, 1u, __ATOMIC_ACQ_REL,
                                                __HIP_MEMORY_SCOPE_AGENT);
        sflag = (old == 479u) ? 1 : 0;
    }
    __syncthreads();
    if (!sflag) return;

    // ---- last block only: outtab finish (proven 1024-thread structure) ------
    if (tid < 480) {
        se[tid] = __hip_atomic_load(&e_tab[tid], __ATOMIC_ACQUIRE,
                                    __HIP_MEMORY_SCOPE_AGENT);
        snn[tid] = (float)hist[(tid >= 2 * NPAT) ? (tid - NPAT) : (tid % NPAT)];
    }
    __syncthreads();

    // yt mean/var: weighted f64 reduction over 480 bins
    {
        double d1 = 0.0, d2 = 0.0;
        if (tid < 480) {
            const double n = (double)snn[tid], e = (double)se[tid];
            d1 = n * e; d2 = n * e * e;
        }
#pragma unroll
        for (int off = 32; off; off >>= 1) {
            d1 += __shfl_xor(d1, off);
            d2 += __shfl_xor(d2, off);
        }
        if (lane == 0) { wpart[w][0] = d1; wpart[w][1] = d2; }
        __syncthreads();
        if (tid == 0) {
            double a = 0.0, b2 = 0.0;
#pragma unroll
            for (int i = 0; i < 16; ++i) { a += wpart[i][0]; b2 += wpart[i][1]; }
            dstat[0] = a; dstat[1] = b2;
        }
        __syncthreads();
    }
    const double mean_yt = dstat[0] / (3.0 * (double)CNT);
    const double var_yt  = dstat[1] / (3.0 * (double)CNT) - mean_yt * mean_yt;

    if (tid < DIMC) {
        const float wm = Wm[tid];
        sA[tid] = gm[tid] * wm * rsqrtf(wm * wm * (float)var_yt + EPS);
        sB[tid] = bem[tid];
        sWo0[tid] = Wo[tid * 2 + 0];
        sWo1[tid] = Wo[tid * 2 + 1];
    }
    __syncthreads();

    const float bo0 = bo[0], bo1 = bo[1];
    for (int idx = w; idx < 480; idx += 16) {
        const float du = se[idx] - (float)mean_yt;
        float a0 = 0.0f, a1 = 0.0f;
#pragma unroll
        for (int i = 0; i < 4; ++i) {
            const int c = lane + 64 * i;
            const float mo = fast_elu(sA[c] * du + sB[c]);
            a0 += mo * sWo0[c];
            a1 += mo * sWo1[c];
        }
#pragma unroll
        for (int off = 32; off; off >>= 1) {
            a0 += __shfl_xor(a0, off);
            a1 += __shfl_xor(a1, off);
        }
        if (lane == 0) { spre0[idx] = a0 + bo0; spre1[idx] = a1 + bo1; }
    }
    __syncthreads();

    {
        double v4[4] = {0.0, 0.0, 0.0, 0.0};
        if (tid < 480) {
            const double n = (double)snn[tid];
            const double p0 = (double)spre0[tid], p1 = (double)spre1[tid];
            v4[0] = n * p0; v4[1] = n * p0 * p0; v4[2] = n * p1; v4[3] = n * p1 * p1;
        }
#pragma unroll
        for (int off = 32; off; off >>= 1)
#pragma unroll
            for (int s = 0; s < 4; ++s) v4[s] += __shfl_xor(v4[s], off);
        if (lane == 0)
#pragma unroll
            for (int s = 0; s < 4; ++s) wpart[w][s] = v4[s];
        __syncthreads();
        if (tid == 0) {
            double a[4] = {0.0, 0.0, 0.0, 0.0};
#pragma unroll
            for (int i = 0; i < 16; ++i)
#pragma unroll
                for (int s = 0; s < 4; ++s) a[s] += wpart[i][s];
#pragma unroll
            for (int s = 0; s < 4; ++s) dstat[2 + s] = a[s];
        }
        __syncthreads();
    }

    if (tid < 480) {
        const double m0 = dstat[2] / (3.0 * (double)CNT);
        const double v0 = dstat[3] / (3.0 * (double)CNT) - m0 * m0;
        const double m1 = dstat[4] / (3.0 * (double)CNT);
        const double v1 = dstat[5] / (3.0 * (double)CNT) - m1 * m1;
        const float sc0 = go[0] * rsqrtf((float)v0 + EPS);
        const float sc1 = go[1] * rsqrtf((float)v1 + EPS);
        ((float2*)out_tab)[tid] =
            make_float2(sc0 * (spre0[tid] - (float)m0) + beo[0],
                        sc1 * (spre1[tid] - (float)m1) + beo[1]);
    }
}

// =============================================================================
// k_write2: streaming table write from codes. 1024 blocks x 256 threads. [proven]
// =============================================================================
__global__ __launch_bounds__(256) void k_write2(const ushort_t* __restrict__ codes,
                                                const float* __restrict__ out_tab,
                                                float* __restrict__ out) {
    __shared__ float2 tb[3 * NPAT];
    const int tid = threadIdx.x;
    for (int i = tid; i < 3 * NPAT; i += 256) tb[i] = ((const float2*)out_tab)[i];
    __syncthreads();
    const size_t gidx = (size_t)blockIdx.x * 256 + tid;
    const ushort4 cv = ((const ushort4*)codes)[gidx];
    const int cc[4] = {cv.x, cv.y, cv.z, cv.w};
    union { float f[24]; float4 v[6]; } u;
#pragma unroll
    for (int r = 0; r < 4; ++r) {
        const int qd = cc[r] & 0xff, qp = cc[r] >> 8;
        const float2 v0 = tb[qd], v1 = tb[NPAT + qd], v2 = tb[2 * NPAT + qp];
        u.f[r * 6 + 0] = v0.x; u.f[r * 6 + 1] = v0.y;
        u.f[r * 6 + 2] = v1.x; u.f[r * 6 + 3] = v1.y;
        u.f[r * 6 + 4] = v2.x; u.f[r * 6 + 5] = v2.y;
    }
    float4* o = (float4*)(out + gidx * 24);
#pragma unroll
    for (int r = 0; r < 6; ++r) o[r] = u.v[r];
}

// =============================================================================
extern "C" void kernel_launch(void* const* d_in, const int* in_sizes, int n_in,
                              void* d_out, int out_size, void* d_ws, size_t ws_size,
                              hipStream_t stream) {
    (void)in_sizes; (void)n_in; (void)out_size; (void)ws_size;
    const float* x = (const float*)d_in[0];
    const int* perms = (const int*)d_in[1];

    PtrPack pk;
    for (int j = 0; j < 3; ++j)
        for (int s = 0; s < 6; ++s)
            pk.p[6 * j + s] = (const float*)d_in[2 + 6 * j + s];

    const float* Wm  = (const float*)d_in[20];
    const float* gm  = (const float*)d_in[22];
    const float* bem = (const float*)d_in[23];
    const float* Wo  = (const float*)d_in[24];
    const float* bo  = (const float*)d_in[25];
    const float* go  = (const float*)d_in[26];
    const float* beo = (const float*)d_in[27];

    // ws layout: [0,1280) u32 hist[320]; [1280,1284) u32 done;
    //            [1536,5376) f32 out_tab[960]; [5632,7552) f32 e_tab[480];
    //            [8192, 8192+2M) u16 codes
    uint*     hist    = (uint*)d_ws;
    uint*     done    = (uint*)((char*)d_ws + 1280);
    float*    out_tab = (float*)((char*)d_ws + 1536);
    float*    e_tab   = (float*)((char*)d_ws + 5632);
    ushort_t* codes   = (ushort_t*)((char*)d_ws + 8192);

    k_zero<<<1, 512, 0, stream>>>(hist);   // zeroes hist[320] + done (word 320)
    k_prep<<<BATCH, 512, 0, stream>>>(x, perms, hist, codes);
    k_etab4<<<480, 1024, 0, stream>>>(pk, hist, e_tab, done,
                                      Wm, gm, bem, Wo, bo, go, beo, out_tab);
    k_write2<<<1024, 256, 0, stream>>>(codes, out_tab, (float*)d_out);
}

// Round 11
// 50.275 us; speedup vs baseline: 1.4679x; 1.4679x over previous
//
#include <hip/hip_runtime.h>
#include <hip/hip_bf16.h>
#include <math.h>

#define BATCH 256
#define SEQL  4096
#define DIMC  256
#define NPAT  160
#define CNT   (BATCH * SEQL)     // per-stream element count (over B,L)
#define EPS   1e-3f

typedef unsigned int uint;
typedef unsigned short ushort_t;

// ---------------- shared helpers ----------------------------------------------
__device__ __forceinline__ int pad_mask(int type) {
    return (type == 0) ? 0 : (type == 1) ? 3 : (type == 2) ? 1 : (type == 3) ? 16 : 24;
}

// tap value for extended-pattern q, index k in [0,6): k==5 is the constant 1.
__device__ __forceinline__ float tap6(int q, int k) {
    if (k == 5) return 1.0f;
    const int type = q >> 5, bits = q & 31;
    const int pm = pad_mask(type);
    if ((pm >> k) & 1) return 0.0f;
    return ((bits >> k) & 1) ? 1.0f : -1.0f;
}

__device__ __forceinline__ float fast_elu(float x) {
    return x > 0.0f ? x : (__expf(x) - 1.0f);
}

__device__ __forceinline__ int pat_type(int t) {
    if (t >= 2 && t < SEQL - 2) return 0;
    if (t == 0) return 1;
    if (t == 1) return 2;
    if (t == SEQL - 2) return 3;
    return 4;
}

struct PtrPack { const float* p[18]; };  // per stream: Wc, bc, g, be, Wf, bf

// =============================================================================
// k_zero: zero hist[320]. Plain kernel node.
// =============================================================================
__global__ __launch_bounds__(512) void k_zero(uint* __restrict__ ws0) {
    if (threadIdx.x < 320) ws0[threadIdx.x] = 0u;
}

// =============================================================================
// k_prep: bit-pack rows (ballot), per-position codes, LDS hist -> global
// atomic hist (1.3 KB total). 256 blocks x 512 threads.  [proven]
// =============================================================================
__global__ __launch_bounds__(512) void k_prep(const float* __restrict__ x,
                                              const int* __restrict__ perms,
                                              uint* __restrict__ hist,
                                              ushort_t* __restrict__ codes) {
    __shared__ uint xw[130];    // bit-packed row, 1-word zero sentinel each end
    __shared__ uint xwI[130];
    __shared__ uint h[2 * NPAT];
    const int b = blockIdx.x, tid = threadIdx.x;
    const int lane = tid & 63;

    for (int i = tid; i < 2 * NPAT; i += 512) h[i] = 0;
    if (tid < 2) { xw[tid * 129] = 0; xwI[tid * 129] = 0; }

    const float* xr = x + (size_t)b * SEQL;
    const int* pr = perms + (size_t)b * SEQL;

#pragma unroll
    for (int it = 0; it < 8; ++it) {
        const int i = it * 512 + tid;
        const unsigned long long m = __ballot(xr[i] > 0.5f);
        if (lane == 0) {
            const int w = 1 + ((it * 512 + (tid & ~63)) >> 5);
            xw[w] = (uint)m;
            xw[w + 1] = (uint)(m >> 32);
        }
    }
    __syncthreads();
#pragma unroll
    for (int it = 0; it < 8; ++it) {
        const int i = it * 512 + tid;
        const int p = pr[i];
        const unsigned long long m = __ballot(((xw[1 + (p >> 5)] >> (p & 31)) & 1u) != 0u);
        if (lane == 0) {
            const int w = 1 + ((it * 512 + (tid & ~63)) >> 5);
            xwI[w] = (uint)m;
            xwI[w + 1] = (uint)(m >> 32);
        }
    }
    __syncthreads();

    const int t0 = tid * 8;
    const int w = (t0 + 30) >> 5;
    const int sh0 = (t0 + 30) & 31;
    const unsigned long long Wd = (unsigned long long)xw[w] | ((unsigned long long)xw[w + 1] << 32);
    const unsigned long long Wi = (unsigned long long)xwI[w] | ((unsigned long long)xwI[w + 1] << 32);
    int c[8];
#pragma unroll
    for (int r = 0; r < 8; ++r) {
        const int t = t0 + r;
        const int type = pat_type(t);
        const int qd = type * 32 + (int)((Wd >> (sh0 + r)) & 31ull);
        const int qp = type * 32 + (int)((Wi >> (sh0 + r)) & 31ull);
        atomicAdd(&h[qd], 1u);
        atomicAdd(&h[NPAT + qp], 1u);
        c[r] = qd | (qp << 8);
    }
    uint4 cv;
    cv.x = (uint)(c[0] | (c[1] << 16));
    cv.y = (uint)(c[2] | (c[3] << 16));
    cv.z = (uint)(c[4] | (c[5] << 16));
    cv.w = (uint)(c[6] | (c[7] << 16));
    *(uint4*)(codes + (size_t)b * SEQL + t0) = cv;
    __syncthreads();

    if (tid < 2 * NPAT) {
        const uint v = h[tid];
        if (v) atomicAdd(&hist[tid], v);
    }
}

// =============================================================================
// k_etab3: e-table, 480 blocks (one per (stream j, pattern q)) x 256 threads
// (one per channel). Fully static code, coefficients in registers, one
// wave-reduce per block. [proven]
// =============================================================================
__global__ __launch_bounds__(256) void k_etab3(PtrPack pk,
                                               const uint* __restrict__ hist,
                                               float* __restrict__ e_tab) {
    const int bid = blockIdx.x;           // 0..479
    const int j = bid / NPAT, q = bid % NPAT;
    const int c = threadIdx.x;            // channel
    const int lane = c & 63, w = c >> 6;  // 4 waves

    __shared__ float sh[NPAT];
    __shared__ float m6p[21][8];
    __shared__ float sM6[21];
    __shared__ float red[4];

    if (c < NPAT) sh[c] = (float)hist[(j == 2 ? NPAT : 0) + c];
    __syncthreads();

    // M6: 168 threads cover 21 entries x 8 chunks of 20 bins (static per thread)
    if (c < 168) {
        const int e = c >> 3, prt = c & 7;
        int k = 0, rem = e;
        while (rem > 5 - k) { rem -= 6 - k; ++k; }
        const int l = k + rem;
        float S = 0.0f;
        for (int qq = prt * 20; qq < prt * 20 + 20; ++qq)
            S += sh[qq] * tap6(qq, k) * tap6(qq, l);
        m6p[e][prt] = S;
    }
    __syncthreads();
    if (c < 21) {
        float S = 0.0f;
#pragma unroll
        for (int p = 0; p < 8; ++p) S += m6p[c][p];
        sM6[c] = S;
    }
    __syncthreads();

    // per-channel BN coefficients — entirely in registers, fully unrolled
    const float* Wc = pk.p[6 * j + 0];
    const float* bc = pk.p[6 * j + 1];
    const float* g  = pk.p[6 * j + 2];
    const float* be = pk.p[6 * j + 3];
    const float* Wf = pk.p[6 * j + 4];
    const float  bf = pk.p[6 * j + 5][0];

    float w6[6];
#pragma unroll
    for (int k = 0; k < 5; ++k) w6[k] = Wc[k * DIMC + c];
    w6[5] = bc[c];

    double Ey = 0.0, Ey2 = 0.0;
    {
        int e = 0;
#pragma unroll
        for (int k = 0; k < 6; ++k) {
#pragma unroll
            for (int l = k; l < 6; ++l, ++e) {
                const double p = (double)w6[k] * (double)w6[l] * (double)sM6[e];
                Ey2 += (l == k) ? p : 2.0 * p;
                if (l == 5) Ey += (double)w6[k] * (double)sM6[e];
            }
        }
    }
    const double mean = Ey / (double)CNT;
    const double var = Ey2 / (double)CNT - mean * mean;
    const float scale = g[c] * rsqrtf((float)var + EPS);

    // this block's pattern taps (uniform across threads)
    float tk[5];
#pragma unroll
    for (int k = 0; k < 5; ++k) tk[k] = tap6(q, k);

    float bn = scale * (w6[5] - (float)mean) + be[c];
#pragma unroll
    for (int k = 0; k < 5; ++k) bn += tk[k] * (scale * w6[k]);
    float v = fast_elu(bn) * Wf[c];

#pragma unroll
    for (int off = 32; off; off >>= 1) v += __shfl_xor(v, off);
    if (lane == 0) red[w] = v;
    __syncthreads();
    if (c == 0) e_tab[bid] = red[0] + red[1] + red[2] + red[3] + bf;
}

// =============================================================================
// k_wfin: 256 blocks x 512 threads. Every block redundantly computes the
// outtab finish (bit-identical across blocks; pattern-per-thread dots, no
// shuffle chains), keeps the 960-float table in LDS, then streams its row.
// =============================================================================
__global__ __launch_bounds__(512) void k_wfin(const ushort_t* __restrict__ codes,
                                              const uint* __restrict__ hist,
                                              const float* __restrict__ e_tab,
                                              const float* __restrict__ Wm,
                                              const float* __restrict__ gm,
                                              const float* __restrict__ bem,
                                              const float* __restrict__ Wo,
                                              const float* __restrict__ bo,
                                              const float* __restrict__ go,
                                              const float* __restrict__ beo,
                                              float* __restrict__ out) {
    const int tid = threadIdx.x;
    const int lane = tid & 63, w = tid >> 6;   // 8 waves

    __shared__ float se[480], snn[480], spre0[480], spre1[480];
    __shared__ float sA[DIMC], sB[DIMC], sWo0[DIMC], sWo1[DIMC];
    __shared__ float2 tb[480];
    __shared__ double wpart[8][4];
    __shared__ double dstat[6];

    // ---- A: load e-table + histogram ----------------------------------------
    if (tid < 480) {
        se[tid] = e_tab[tid];
        snn[tid] = (float)hist[(tid >= 2 * NPAT) ? (tid - NPAT) : (tid % NPAT)];
    }
    __syncthreads();

    // ---- B: yt mean/var (weighted f64 over 480 bins) ------------------------
    {
        double d1 = 0.0, d2 = 0.0;
        if (tid < 480) {
            const double n = (double)snn[tid], e = (double)se[tid];
            d1 = n * e; d2 = n * e * e;
        }
#pragma unroll
        for (int off = 32; off; off >>= 1) {
            d1 += __shfl_xor(d1, off);
            d2 += __shfl_xor(d2, off);
        }
        if (lane == 0) { wpart[w][0] = d1; wpart[w][1] = d2; }
        __syncthreads();
        if (tid == 0) {
            double a = 0.0, b2 = 0.0;
#pragma unroll
            for (int i = 0; i < 8; ++i) { a += wpart[i][0]; b2 += wpart[i][1]; }
            dstat[0] = a; dstat[1] = b2;
        }
        __syncthreads();
    }
    const double mean_yt = dstat[0] / (3.0 * (double)CNT);
    const double var_yt  = dstat[1] / (3.0 * (double)CNT) - mean_yt * mean_yt;

    // ---- C: middle-unit affine coefficients ---------------------------------
    if (tid < DIMC) {
        const float wm = Wm[tid];
        sA[tid] = gm[tid] * wm * rsqrtf(wm * wm * (float)var_yt + EPS);
        sB[tid] = bem[tid];
        sWo0[tid] = Wo[tid * 2 + 0];
        sWo1[tid] = Wo[tid * 2 + 1];
    }
    __syncthreads();

    // ---- D: pre-activations, ONE PATTERN PER THREAD (no shuffles) -----------
    if (tid < 480) {
        const float du = se[tid] - (float)mean_yt;
        float a0 = bo[0], a1 = bo[1];
#pragma unroll 4
        for (int c = 0; c < DIMC; ++c) {
            const float mo = fast_elu(sA[c] * du + sB[c]);
            a0 += mo * sWo0[c];
            a1 += mo * sWo1[c];
        }
        spre0[tid] = a0;
        spre1[tid] = a1;
    }
    __syncthreads();

    // ---- E: output BN stats (4 weighted f64 sums) ---------------------------
    {
        double v4[4] = {0.0, 0.0, 0.0, 0.0};
        if (tid < 480) {
            const double n = (double)snn[tid];
            const double p0 = (double)spre0[tid], p1 = (double)spre1[tid];
            v4[0] = n * p0; v4[1] = n * p0 * p0; v4[2] = n * p1; v4[3] = n * p1 * p1;
        }
#pragma unroll
        for (int off = 32; off; off >>= 1)
#pragma unroll
            for (int s = 0; s < 4; ++s) v4[s] += __shfl_xor(v4[s], off);
        if (lane == 0)
#pragma unroll
            for (int s = 0; s < 4; ++s) wpart[w][s] = v4[s];
        __syncthreads();
        if (tid == 0) {
            double a[4] = {0.0, 0.0, 0.0, 0.0};
#pragma unroll
            for (int i = 0; i < 8; ++i)
#pragma unroll
                for (int s = 0; s < 4; ++s) a[s] += wpart[i][s];
#pragma unroll
            for (int s = 0; s < 4; ++s) dstat[2 + s] = a[s];
        }
        __syncthreads();
    }

    // ---- F: final output table (LDS) ----------------------------------------
    if (tid < 480) {
        const double m0 = dstat[2] / (3.0 * (double)CNT);
        const double v0 = dstat[3] / (3.0 * (double)CNT) - m0 * m0;
        const double m1 = dstat[4] / (3.0 * (double)CNT);
        const double v1 = dstat[5] / (3.0 * (double)CNT) - m1 * m1;
        const float sc0 = go[0] * rsqrtf((float)v0 + EPS);
        const float sc1 = go[1] * rsqrtf((float)v1 + EPS);
        tb[tid] = make_float2(sc0 * (spre0[tid] - (float)m0) + beo[0],
                              sc1 * (spre1[tid] - (float)m1) + beo[1]);
    }
    __syncthreads();

    // ---- G: stream this block's row from codes (8 positions/thread) ---------
    const int b = blockIdx.x;
    const uint4 cw = *(const uint4*)(codes + (size_t)b * SEQL + tid * 8);
    const uint cw4[4] = {cw.x, cw.y, cw.z, cw.w};
    union { float f[48]; float4 v[12]; } u;
#pragma unroll
    for (int r = 0; r < 8; ++r) {
        const uint code = (cw4[r >> 1] >> ((r & 1) * 16)) & 0xffffu;
        const int qd = (int)(code & 0xffu), qp = (int)(code >> 8);
        const float2 v0 = tb[qd], v1 = tb[NPAT + qd], v2 = tb[2 * NPAT + qp];
        u.f[r * 6 + 0] = v0.x; u.f[r * 6 + 1] = v0.y;
        u.f[r * 6 + 2] = v1.x; u.f[r * 6 + 3] = v1.y;
        u.f[r * 6 + 4] = v2.x; u.f[r * 6 + 5] = v2.y;
    }
    float4* o = (float4*)(out + ((size_t)b * SEQL + (size_t)tid * 8) * 6);
#pragma unroll
    for (int r = 0; r < 12; ++r) o[r] = u.v[r];
}

// =============================================================================
extern "C" void kernel_launch(void* const* d_in, const int* in_sizes, int n_in,
                              void* d_out, int out_size, void* d_ws, size_t ws_size,
                              hipStream_t stream) {
    (void)in_sizes; (void)n_in; (void)out_size; (void)ws_size;
    const float* x = (const float*)d_in[0];
    const int* perms = (const int*)d_in[1];

    PtrPack pk;
    for (int j = 0; j < 3; ++j)
        for (int s = 0; s < 6; ++s)
            pk.p[6 * j + s] = (const float*)d_in[2 + 6 * j + s];

    const float* Wm  = (const float*)d_in[20];
    const float* gm  = (const float*)d_in[22];
    const float* bem = (const float*)d_in[23];
    const float* Wo  = (const float*)d_in[24];
    const float* bo  = (const float*)d_in[25];
    const float* go  = (const float*)d_in[26];
    const float* beo = (const float*)d_in[27];

    // ws layout: [0,1280) u32 hist[320]; [5632,7552) f32 e_tab[480];
    //            [8192, 8192+2M) u16 codes
    uint*     hist  = (uint*)d_ws;
    float*    e_tab = (float*)((char*)d_ws + 5632);
    ushort_t* codes = (ushort_t*)((char*)d_ws + 8192);

    k_zero<<<1, 512, 0, stream>>>(hist);
    k_prep<<<BATCH, 512, 0, stream>>>(x, perms, hist, codes);
    k_etab3<<<480, 256, 0, stream>>>(pk, hist, e_tab);
    k_wfin<<<BATCH, 512, 0, stream>>>(codes, hist, e_tab,
                                      Wm, gm, bem, Wo, bo, go, beo, (float*)d_out);
}